// Round 14
// baseline (376.824 us; speedup 1.0000x reference)
//
#include <hip/hip_runtime.h>
#include <hip/hip_fp16.h>

#define N_ROWS 100000
#define NNODES 150000
#define D 32
#define NEDGE 5000000
#define BINSHIFT 7
#define BINSZ 128                          // nodes per bin
#define NBINS 1172                         // ceil(150000 / 128)
#define NBLK 512                           // scatter/count blocks
#define SCT 1024                           // threads per scatter/count block
#define CPB ((NEDGE + NBLK - 1) / NBLK)    // 9766 edges per block
#define NCOUNTS (NBINS * NBLK)             // 600064
#define SCAN_ITEMS 1024
#define NSCAN (NCOUNTS / SCAN_ITEMS)       // 586 (exact)

#define NB 8                               // src buckets (octiles)
#define BDIV 18750                         // 150000 / 8

#define LIN_T 128                          // threads per linear block
#define LIN_RPB 256                        // rows per linear block (2 rows/thread)
#define LIN_GRID ((NNODES + LIN_RPB - 1) / LIN_RPB)  // 586

// ---------------- stage 1: per-(block,bin) counts matrix (no global atomics) ----------------

__global__ void count_kernel(const int* __restrict__ dst, int* __restrict__ counts) {
    __shared__ int h[4 * NBINS];
    const int t = threadIdx.x;
    const int sub = ((t >> 6) & 3) * NBINS;
    for (int b = t; b < 4 * NBINS; b += SCT) h[b] = 0;
    __syncthreads();
    const int e0 = blockIdx.x * CPB;
    const int e1 = min(e0 + CPB, NEDGE);
    for (int i = e0 + t; i < e1; i += SCT) atomicAdd(&h[sub + (dst[i] >> BINSHIFT)], 1);
    __syncthreads();
    for (int b = t; b < NBINS; b += SCT)
        counts[b * NBLK + blockIdx.x] = h[b] + h[NBINS + b] + h[2 * NBINS + b] + h[3 * NBINS + b];
}

// ---------------- stage 2: device-wide exclusive scan of counts ----------------

__global__ void scanA(const int* __restrict__ counts, int* __restrict__ partials) {
    __shared__ int s[256];
    const int t = threadIdx.x;
    const int base = blockIdx.x * SCAN_ITEMS + t * 4;
    int sum = 0;
#pragma unroll
    for (int k = 0; k < 4; ++k) sum += counts[base + k];
    s[t] = sum;
    __syncthreads();
    for (int off = 128; off > 0; off >>= 1) {
        if (t < off) s[t] += s[t + off];
        __syncthreads();
    }
    if (t == 0) partials[blockIdx.x] = s[0];
}

__global__ void scanB(int* __restrict__ partials) {
    __shared__ int s[256];
    __shared__ int carry;
    const int t = threadIdx.x;
    if (t == 0) carry = 0;
    __syncthreads();
    for (int c = 0; c < (NSCAN + 255) / 256; ++c) {
        int idx = c * 256 + t;
        int v = (idx < NSCAN) ? partials[idx] : 0;
        s[t] = v;
        __syncthreads();
        for (int off = 1; off < 256; off <<= 1) {
            int tmp = (t >= off) ? s[t - off] : 0;
            __syncthreads();
            s[t] += tmp;
            __syncthreads();
        }
        if (idx < NSCAN) partials[idx] = carry + s[t] - v;  // exclusive
        __syncthreads();
        if (t == 0) carry += s[255];
        __syncthreads();
    }
}

__global__ void scanC(const int* __restrict__ counts, const int* __restrict__ partials,
                      int* __restrict__ bases, int* __restrict__ binPtr) {
    __shared__ int s[256];
    const int t = threadIdx.x;
    const int base = blockIdx.x * SCAN_ITEMS + t * 4;
    int c[4];
    int sum = 0;
#pragma unroll
    for (int k = 0; k < 4; ++k) { c[k] = counts[base + k]; sum += c[k]; }
    s[t] = sum;
    __syncthreads();
    for (int off = 1; off < 256; off <<= 1) {
        int v = (t >= off) ? s[t - off] : 0;
        __syncthreads();
        s[t] += v;
        __syncthreads();
    }
    int run = partials[blockIdx.x] + ((t == 0) ? 0 : s[t - 1]);
#pragma unroll
    for (int k = 0; k < 4; ++k) {
        int idx = base + k;
        bases[idx] = run;
        if ((idx & (NBLK - 1)) == 0) binPtr[idx / NBLK] = run;
        run += c[k];
    }
    if (blockIdx.x == 0 && t == 0) binPtr[NBINS] = NEDGE;
}

// ---------------- stage 3: LDS-staged scatter — group-per-bin copy ----------------

__global__ void __launch_bounds__(SCT, 2)
scatter3(const int* __restrict__ src, const int* __restrict__ dst,
         const int* __restrict__ bases, unsigned int* __restrict__ binned) {
    __shared__ int cnt[NBINS];          // counts, then cursor
    __shared__ int lb[NBINS + 1];       // local exclusive prefix
    __shared__ int gb[NBINS];           // global base per bin for this block
    __shared__ int ssum[SCT];
    __shared__ unsigned int staged[CPB];

    const int t = threadIdx.x;
    const int e0 = blockIdx.x * CPB;
    const int e1 = min(e0 + CPB, NEDGE);
    const int n = e1 - e0;

    for (int b = t; b < NBINS; b += SCT) {
        cnt[b] = 0;
        gb[b] = bases[b * NBLK + blockIdx.x];
    }
    __syncthreads();
    for (int i = e0 + t; i < e1; i += SCT) atomicAdd(&cnt[dst[i] >> BINSHIFT], 1);
    __syncthreads();

    const int i0 = 2 * t, i1 = 2 * t + 1;
    const int c0 = (i0 < NBINS) ? cnt[i0] : 0;
    const int c1 = (i1 < NBINS) ? cnt[i1] : 0;
    ssum[t] = c0 + c1;
    __syncthreads();
    for (int off = 1; off < SCT; off <<= 1) {
        int v = (t >= off) ? ssum[t - off] : 0;
        __syncthreads();
        ssum[t] += v;
        __syncthreads();
    }
    const int excl = (t == 0) ? 0 : ssum[t - 1];
    if (i0 < NBINS) lb[i0] = excl;
    if (i1 < NBINS) lb[i1] = excl + c0;
    if (t == 0) lb[NBINS] = n;
    __syncthreads();

    for (int b = t; b < NBINS; b += SCT) cnt[b] = lb[b];
    __syncthreads();
    for (int i = e0 + t; i < e1; i += SCT) {
        const int dv = dst[i];
        const int bn = dv >> BINSHIFT;
        const int slot = atomicAdd(&cnt[bn], 1);
        staged[slot] = ((unsigned)(dv & (BINSZ - 1)) << 18) | (unsigned)src[i];
    }
    __syncthreads();

    const int grp = t >> 4;
    const int lane = t & 15;
    for (int b = grp; b < NBINS; b += 64) {
        const int lo = lb[b];
        const int hi = lb[b + 1];
        const int gbase = gb[b] - lo;
        for (int s2 = lo + lane; s2 < hi; s2 += 16)
            binned[gbase + s2] = staged[s2];
    }
}

// ---------------- stage 4: per-bin counting sort by (dstLocal, srcOctile) ----------------

__global__ void fine_sort8(const int* __restrict__ binPtr, const unsigned int* __restrict__ binned,
                           int* __restrict__ qrowptr, int* __restrict__ srcSorted) {
    __shared__ int cnt[BINSZ * NB];   // 1024 keys
    __shared__ int cur[BINSZ * NB];
    const int t = threadIdx.x;        // 1024 threads, one key each
    const int bin = blockIdx.x;
    const int e0 = binPtr[bin];
    const int e1 = binPtr[bin + 1];

    cnt[t] = 0;
    __syncthreads();
    for (int e = e0 + t; e < e1; e += 1024) {
        const unsigned u = binned[e];
        const unsigned s = u & 0x3FFFFu;
        const int key = (int)((u >> 18) * NB) + (int)(s / BDIV);
        atomicAdd(&cnt[key], 1);
    }
    __syncthreads();
    cur[t] = cnt[t];
    __syncthreads();
    for (int off = 1; off < BINSZ * NB; off <<= 1) {
        int v = (t >= off) ? cur[t - off] : 0;
        __syncthreads();
        cur[t] += v;
        __syncthreads();
    }
    {
        const int excl = cur[t] - cnt[t];
        qrowptr[bin * (BINSZ * NB) + t] = e0 + excl;
        cur[t] = excl;
    }
    __syncthreads();
    for (int e = e0 + t; e < e1; e += 1024) {
        const unsigned u = binned[e];
        const unsigned s = u & 0x3FFFFu;
        const int key = (int)((u >> 18) * NB) + (int)(s / BDIV);
        const int p = atomicAdd(&cur[key], 1);
        srcSorted[e0 + p] = (int)s;
    }
    if (bin == 0 && t == 0) qrowptr[NBINS * (BINSZ * NB)] = NEDGE;  // sentinel
}

// ---------------- layer-0 linear: row-per-thread GEMV (proven round 11) ----------------

template <int MODE>
__global__ void __launch_bounds__(LIN_T)
linear_rows(const float* __restrict__ xa, const float* __restrict__ xb,
            const float* __restrict__ W, const float* __restrict__ b,
            __half* __restrict__ H) {
    __shared__ float xs[LIN_RPB * 33];   // also reused as output staging
    __shared__ float Ws[32 * 36];
    __shared__ float bs[32];
    const int t = threadIdx.x;

    for (int i = t; i < 1024; i += LIN_T) {
        const int c = i >> 5, k = i & 31;
        Ws[k * 36 + c] = W[i];
    }
    if (t < 32) bs[t] = b[t];

    const long long ebase = (long long)blockIdx.x * (LIN_RPB * 32);
#pragma unroll 4
    for (int i = 0; i < (LIN_RPB * 32) / LIN_T; ++i) {
        const long long e = ebase + i * LIN_T + t;
        const int flat = i * LIN_T + t;
        float v = 0.0f;
        if (e < (long long)NNODES * 32) {
            if (MODE == 0) {
                v = (e < (long long)N_ROWS * 32) ? xa[e] : xb[e - (long long)N_ROWS * 32];
            } else {
                v = fmaxf(xa[e], 0.0f);
            }
        }
        xs[(flat >> 5) * 33 + (flat & 31)] = v;
    }
    __syncthreads();

    float a0[32], a1[32];
#pragma unroll
    for (int c = 0; c < 32; ++c) { a0[c] = bs[c]; a1[c] = bs[c]; }
    const int r0 = 2 * t, r1 = 2 * t + 1;
#pragma unroll
    for (int k = 0; k < 32; ++k) {
        const float x0 = xs[r0 * 33 + k];
        const float x1 = xs[r1 * 33 + k];
        const float4* wr = (const float4*)&Ws[k * 36];
#pragma unroll
        for (int q = 0; q < 8; ++q) {
            const float4 w = wr[q];
            a0[4 * q + 0] = fmaf(x0, w.x, a0[4 * q + 0]);
            a0[4 * q + 1] = fmaf(x0, w.y, a0[4 * q + 1]);
            a0[4 * q + 2] = fmaf(x0, w.z, a0[4 * q + 2]);
            a0[4 * q + 3] = fmaf(x0, w.w, a0[4 * q + 3]);
            a1[4 * q + 0] = fmaf(x1, w.x, a1[4 * q + 0]);
            a1[4 * q + 1] = fmaf(x1, w.y, a1[4 * q + 1]);
            a1[4 * q + 2] = fmaf(x1, w.z, a1[4 * q + 2]);
            a1[4 * q + 3] = fmaf(x1, w.w, a1[4 * q + 3]);
        }
    }
    __syncthreads();

    unsigned* os = (unsigned*)xs;
#pragma unroll
    for (int p = 0; p < 16; ++p) {
        __half2 h0 = __floats2half2_rn(a0[2 * p], a0[2 * p + 1]);
        __half2 h1 = __floats2half2_rn(a1[2 * p], a1[2 * p + 1]);
        os[r0 * 17 + p] = *(unsigned*)&h0;
        os[r1 * 17 + p] = *(unsigned*)&h1;
    }
    __syncthreads();
    unsigned* H2 = (unsigned*)H;
    const long long obase = (long long)blockIdx.x * (LIN_RPB * 16);
#pragma unroll 4
    for (int i = 0; i < (LIN_RPB * 16) / LIN_T; ++i) {
        const long long o = obase + i * LIN_T + t;
        const int flat = i * LIN_T + t;
        if (o < (long long)NNODES * 16)
            H2[o] = os[(flat >> 4) * 17 + (flat & 15)];
    }
}

// ---------------- fused aggregation (+ReLU) (+next linear via LDS-GEMV) ----------------
// 16 lanes per dst row, half2 per lane, unroll 8; nt loads for srcSorted stream.
// MODE 0: epilogue = relu + linear(W,b) -> Hout fp16 (LDS staging + broadcast GEMV, no shfl)
// MODE 1: epilogue = relu -> out f32
template <int MODE>
__global__ void agg_fused2(const int* __restrict__ qrowptr, const int* __restrict__ srcSorted,
                           const __half* __restrict__ Hin, const float* __restrict__ W,
                           const float* __restrict__ b, __half* __restrict__ Hout,
                           float* __restrict__ out) {
    __shared__ float xs[16 * 33];   // 16 staged rows, stride 33 (2-way conflicts only)
    __shared__ float Ws[32 * 36];
    __shared__ float bs[32];
    const int tid = threadIdx.x;
    const int r = tid >> 4;         // group = row-in-block
    const int j = tid & 15;

    if (MODE == 0) {
        for (int i = tid; i < 1024; i += 256) {
            const int c = i >> 5, k = i & 31;
            Ws[k * 36 + c] = W[i];
        }
        if (tid < 32) bs[tid] = b[tid];
    }

    const int d = blockIdx.x * 16 + r;
    const unsigned int* __restrict__ H2 = (const unsigned int*)Hin;

    int e = qrowptr[d * NB];
    const int eEnd = qrowptr[d * NB + NB];
    float2 acc = __half22float2(((const __half2*)Hin)[d * 16 + j]);  // self-loop
    for (; e + 7 < eEnd; e += 8) {
        int s[8];
#pragma unroll
        for (int k = 0; k < 8; ++k) s[k] = __builtin_nontemporal_load(srcSorted + e + k);
        unsigned int v[8];
#pragma unroll
        for (int k = 0; k < 8; ++k) v[k] = H2[s[k] * 16 + j];
#pragma unroll
        for (int k = 0; k < 8; ++k) {
            const float2 f = __half22float2(*(const __half2*)&v[k]);
            acc.x += f.x;
            acc.y += f.y;
        }
    }
    for (; e < eEnd; ++e) {
        const unsigned int v = H2[__builtin_nontemporal_load(srcSorted + e) * 16 + j];
        const float2 f = __half22float2(*(const __half2*)&v);
        acc.x += f.x;
        acc.y += f.y;
    }

    if (MODE == 1) {
        acc.x = fmaxf(acc.x, 0.0f);
        acc.y = fmaxf(acc.y, 0.0f);
        ((float2*)out)[d * 16 + j] = acc;
        return;
    }

    // stage relu(acc) to LDS, then per-thread GEMV for its own 2 output columns
    xs[r * 33 + 2 * j] = fmaxf(acc.x, 0.0f);
    xs[r * 33 + 2 * j + 1] = fmaxf(acc.y, 0.0f);
    __syncthreads();

    float n0 = bs[2 * j], n1 = bs[2 * j + 1];
#pragma unroll
    for (int k = 0; k < 32; ++k) {
        const float x = xs[r * 33 + k];          // broadcast within 16-lane group
        n0 = fmaf(x, Ws[k * 36 + 2 * j], n0);    // broadcast across groups
        n1 = fmaf(x, Ws[k * 36 + 2 * j + 1], n1);
    }
    __half2 h = __floats2half2_rn(n0, n1);
    ((unsigned*)Hout)[d * 16 + j] = *(unsigned*)&h;
}

// ---------------- launch ----------------

extern "C" void kernel_launch(void* const* d_in, const int* in_sizes, int n_in,
                              void* d_out, int out_size, void* d_ws, size_t ws_size,
                              hipStream_t stream) {
    const float* row_embed = (const float*)d_in[0];
    const float* col_embed = (const float*)d_in[1];
    const float* W0 = (const float*)d_in[2];
    const float* b0 = (const float*)d_in[3];
    const float* W1 = (const float*)d_in[4];
    const float* b1 = (const float*)d_in[5];
    const float* W2 = (const float*)d_in[6];
    const float* b2 = (const float*)d_in[7];
    const int* ei = (const int*)d_in[8];
    const int* src = ei;
    const int* dst = ei + NEDGE;
    float* out = (float*)d_out;

    // workspace carve-up (~65 MB); qrowptr ALIASES counts+bases (dead after scatter3)
    __half* H0 = (__half*)d_ws;                                       // 9.6 MB
    __half* H1 = H0 + (size_t)NNODES * D;                             // 9.6 MB
    unsigned int* binned = (unsigned int*)(H1 + (size_t)NNODES * D);  // 20 MB
    int* srcSorted = (int*)(binned + NEDGE);                          // 20 MB
    int* counts = srcSorted + NEDGE;                                  // 2.4 MB
    int* bases = counts + NCOUNTS;                                    // 2.4 MB
    int* partials = bases + NCOUNTS;                                  // 586
    int* binPtr = partials + NSCAN;                                   // NBINS+1
    int* qrowptr = counts;  // NBINS*1024+1 ints, aliases counts+bases

    const int agg_grid = NNODES / 16;  // 9375

    // CSR build — atomic-free counting sort (rebuilt every call; stateless)
    count_kernel<<<NBLK, SCT, 0, stream>>>(dst, counts);
    scanA<<<NSCAN, 256, 0, stream>>>(counts, partials);
    scanB<<<1, 256, 0, stream>>>(partials);
    scanC<<<NSCAN, 256, 0, stream>>>(counts, partials, bases, binPtr);
    scatter3<<<NBLK, SCT, 0, stream>>>(src, dst, bases, binned);
    fine_sort8<<<NBINS, 1024, 0, stream>>>(binPtr, binned, qrowptr, srcSorted);

    // layer chain: linear0, then 3 fused agg(+linear) kernels
    linear_rows<0><<<LIN_GRID, LIN_T, 0, stream>>>(row_embed, col_embed, W0, b0, H0);
    agg_fused2<0><<<agg_grid, 256, 0, stream>>>(qrowptr, srcSorted, H0, W1, b1, H1, nullptr);
    agg_fused2<0><<<agg_grid, 256, 0, stream>>>(qrowptr, srcSorted, H1, W2, b2, H0, nullptr);
    agg_fused2<1><<<agg_grid, 256, 0, stream>>>(qrowptr, srcSorted, H0, nullptr, nullptr, nullptr, out);

    (void)in_sizes; (void)n_in; (void)out_size; (void)ws_size;
}

// Round 15
// 329.530 us; speedup vs baseline: 1.1435x; 1.1435x over previous
//
#include <hip/hip_runtime.h>
#include <hip/hip_fp16.h>

#define N_ROWS 100000
#define NNODES 150000
#define D 32
#define NEDGE 5000000
#define BINSHIFT 7
#define BINSZ 128                          // nodes per bin
#define NBINS 1172                         // ceil(150000 / 128)
#define NBLK 512                           // scatter/count blocks
#define SCT 1024                           // threads per scatter/count block
#define CPB 9768                           // edges per block (mult of 8 -> 16B aligned)
#define NCOUNTS (NBINS * NBLK)             // 600064
#define SCAN_ITEMS 1024
#define NSCAN (NCOUNTS / SCAN_ITEMS)       // 586 (exact)

#define NB 8                               // src buckets (octiles)
#define BDIV 18750                         // 150000 / 8

#define LIN_T 128                          // threads per linear block
#define LIN_RPB 256                        // rows per linear block (2 rows/thread)
#define LIN_GRID ((NNODES + LIN_RPB - 1) / LIN_RPB)  // 586

// ---------------- stage 1: per-(block,bin) counts matrix (no global atomics) ----------------

__global__ void count_kernel(const int* __restrict__ dst, int* __restrict__ counts) {
    __shared__ int h[4 * NBINS];
    const int t = threadIdx.x;
    const int sub = ((t >> 6) & 3) * NBINS;
    for (int b = t; b < 4 * NBINS; b += SCT) h[b] = 0;
    __syncthreads();
    const int e0 = blockIdx.x * CPB;
    const int e1 = min(e0 + CPB, NEDGE);
    const int nvec = (e1 - e0) & ~3;       // chunk sizes are multiples of 4
    const int4* d4 = (const int4*)(dst + e0);  // e0 16B-aligned (CPB%4==0, base 16B)
    for (int i = t; i * 4 < nvec; i += SCT) {
        const int4 v = d4[i];
        atomicAdd(&h[sub + (v.x >> BINSHIFT)], 1);
        atomicAdd(&h[sub + (v.y >> BINSHIFT)], 1);
        atomicAdd(&h[sub + (v.z >> BINSHIFT)], 1);
        atomicAdd(&h[sub + (v.w >> BINSHIFT)], 1);
    }
    for (int i = e0 + nvec + t; i < e1; i += SCT) atomicAdd(&h[sub + (dst[i] >> BINSHIFT)], 1);
    __syncthreads();
    for (int b = t; b < NBINS; b += SCT)
        counts[b * NBLK + blockIdx.x] = h[b] + h[NBINS + b] + h[2 * NBINS + b] + h[3 * NBINS + b];
}

// ---------------- stage 2: device-wide exclusive scan of counts ----------------

__global__ void scanA(const int* __restrict__ counts, int* __restrict__ partials) {
    __shared__ int s[256];
    const int t = threadIdx.x;
    const int base = blockIdx.x * SCAN_ITEMS + t * 4;
    int sum = 0;
#pragma unroll
    for (int k = 0; k < 4; ++k) sum += counts[base + k];
    s[t] = sum;
    __syncthreads();
    for (int off = 128; off > 0; off >>= 1) {
        if (t < off) s[t] += s[t + off];
        __syncthreads();
    }
    if (t == 0) partials[blockIdx.x] = s[0];
}

__global__ void scanB(int* __restrict__ partials) {
    __shared__ int s[256];
    __shared__ int carry;
    const int t = threadIdx.x;
    if (t == 0) carry = 0;
    __syncthreads();
    for (int c = 0; c < (NSCAN + 255) / 256; ++c) {
        int idx = c * 256 + t;
        int v = (idx < NSCAN) ? partials[idx] : 0;
        s[t] = v;
        __syncthreads();
        for (int off = 1; off < 256; off <<= 1) {
            int tmp = (t >= off) ? s[t - off] : 0;
            __syncthreads();
            s[t] += tmp;
            __syncthreads();
        }
        if (idx < NSCAN) partials[idx] = carry + s[t] - v;  // exclusive
        __syncthreads();
        if (t == 0) carry += s[255];
        __syncthreads();
    }
}

__global__ void scanC(const int* __restrict__ counts, const int* __restrict__ partials,
                      int* __restrict__ bases, int* __restrict__ binPtr) {
    __shared__ int s[256];
    const int t = threadIdx.x;
    const int base = blockIdx.x * SCAN_ITEMS + t * 4;
    int c[4];
    int sum = 0;
#pragma unroll
    for (int k = 0; k < 4; ++k) { c[k] = counts[base + k]; sum += c[k]; }
    s[t] = sum;
    __syncthreads();
    for (int off = 1; off < 256; off <<= 1) {
        int v = (t >= off) ? s[t - off] : 0;
        __syncthreads();
        s[t] += v;
        __syncthreads();
    }
    int run = partials[blockIdx.x] + ((t == 0) ? 0 : s[t - 1]);
#pragma unroll
    for (int k = 0; k < 4; ++k) {
        int idx = base + k;
        bases[idx] = run;
        if ((idx & (NBLK - 1)) == 0) binPtr[idx / NBLK] = run;
        run += c[k];
    }
    if (blockIdx.x == 0 && t == 0) binPtr[NBINS] = NEDGE;
}

// ---------------- stage 3: LDS-staged scatter — group-per-bin copy ----------------

__global__ void __launch_bounds__(SCT, 2)
scatter3(const int* __restrict__ src, const int* __restrict__ dst,
         const int* __restrict__ bases, unsigned int* __restrict__ binned) {
    __shared__ int cnt[NBINS];          // counts, then cursor
    __shared__ int lb[NBINS + 1];       // local exclusive prefix
    __shared__ int gb[NBINS];           // global base per bin for this block
    __shared__ int ssum[SCT];
    __shared__ unsigned int staged[CPB];

    const int t = threadIdx.x;
    const int e0 = blockIdx.x * CPB;
    const int e1 = min(e0 + CPB, NEDGE);
    const int n = e1 - e0;

    for (int b = t; b < NBINS; b += SCT) {
        cnt[b] = 0;
        gb[b] = bases[b * NBLK + blockIdx.x];
    }
    __syncthreads();
    for (int i = e0 + t; i < e1; i += SCT) atomicAdd(&cnt[dst[i] >> BINSHIFT], 1);
    __syncthreads();

    const int i0 = 2 * t, i1 = 2 * t + 1;
    const int c0 = (i0 < NBINS) ? cnt[i0] : 0;
    const int c1 = (i1 < NBINS) ? cnt[i1] : 0;
    ssum[t] = c0 + c1;
    __syncthreads();
    for (int off = 1; off < SCT; off <<= 1) {
        int v = (t >= off) ? ssum[t - off] : 0;
        __syncthreads();
        ssum[t] += v;
        __syncthreads();
    }
    const int excl = (t == 0) ? 0 : ssum[t - 1];
    if (i0 < NBINS) lb[i0] = excl;
    if (i1 < NBINS) lb[i1] = excl + c0;
    if (t == 0) lb[NBINS] = n;
    __syncthreads();

    for (int b = t; b < NBINS; b += SCT) cnt[b] = lb[b];
    __syncthreads();
    for (int i = e0 + t; i < e1; i += SCT) {
        const int dv = dst[i];
        const int bn = dv >> BINSHIFT;
        const int slot = atomicAdd(&cnt[bn], 1);
        staged[slot] = ((unsigned)(dv & (BINSZ - 1)) << 18) | (unsigned)src[i];
    }
    __syncthreads();

    const int grp = t >> 4;
    const int lane = t & 15;
    for (int b = grp; b < NBINS; b += 64) {
        const int lo = lb[b];
        const int hi = lb[b + 1];
        const int gbase = gb[b] - lo;
        for (int s2 = lo + lane; s2 < hi; s2 += 16)
            binned[gbase + s2] = staged[s2];
    }
}

// ---------------- stage 4: per-bin counting sort by (dstLocal, srcOctile) ----------------

__global__ void fine_sort8(const int* __restrict__ binPtr, const unsigned int* __restrict__ binned,
                           int* __restrict__ qrowptr, int* __restrict__ srcSorted) {
    __shared__ int cnt[BINSZ * NB];   // 1024 keys
    __shared__ int cur[BINSZ * NB];
    const int t = threadIdx.x;        // 1024 threads, one key each
    const int bin = blockIdx.x;
    const int e0 = binPtr[bin];
    const int e1 = binPtr[bin + 1];

    cnt[t] = 0;
    __syncthreads();
    for (int e = e0 + t; e < e1; e += 1024) {
        const unsigned u = binned[e];
        const unsigned s = u & 0x3FFFFu;
        const int key = (int)((u >> 18) * NB) + (int)(s / BDIV);
        atomicAdd(&cnt[key], 1);
    }
    __syncthreads();
    cur[t] = cnt[t];
    __syncthreads();
    for (int off = 1; off < BINSZ * NB; off <<= 1) {
        int v = (t >= off) ? cur[t - off] : 0;
        __syncthreads();
        cur[t] += v;
        __syncthreads();
    }
    {
        const int excl = cur[t] - cnt[t];
        qrowptr[bin * (BINSZ * NB) + t] = e0 + excl;
        cur[t] = excl;
    }
    __syncthreads();
    for (int e = e0 + t; e < e1; e += 1024) {
        const unsigned u = binned[e];
        const unsigned s = u & 0x3FFFFu;
        const int key = (int)((u >> 18) * NB) + (int)(s / BDIV);
        const int p = atomicAdd(&cur[key], 1);
        srcSorted[e0 + p] = (int)s;
    }
    if (bin == 0 && t == 0) qrowptr[NBINS * (BINSZ * NB)] = NEDGE;  // sentinel
}

// ---------------- layer-0 linear: row-per-thread GEMV (proven round 11) ----------------

template <int MODE>
__global__ void __launch_bounds__(LIN_T)
linear_rows(const float* __restrict__ xa, const float* __restrict__ xb,
            const float* __restrict__ W, const float* __restrict__ b,
            __half* __restrict__ H) {
    __shared__ float xs[LIN_RPB * 33];   // also reused as output staging
    __shared__ float Ws[32 * 36];
    __shared__ float bs[32];
    const int t = threadIdx.x;

    for (int i = t; i < 1024; i += LIN_T) {
        const int c = i >> 5, k = i & 31;
        Ws[k * 36 + c] = W[i];
    }
    if (t < 32) bs[t] = b[t];

    const long long ebase = (long long)blockIdx.x * (LIN_RPB * 32);
#pragma unroll 4
    for (int i = 0; i < (LIN_RPB * 32) / LIN_T; ++i) {
        const long long e = ebase + i * LIN_T + t;
        const int flat = i * LIN_T + t;
        float v = 0.0f;
        if (e < (long long)NNODES * 32) {
            if (MODE == 0) {
                v = (e < (long long)N_ROWS * 32) ? xa[e] : xb[e - (long long)N_ROWS * 32];
            } else {
                v = fmaxf(xa[e], 0.0f);
            }
        }
        xs[(flat >> 5) * 33 + (flat & 31)] = v;
    }
    __syncthreads();

    float a0[32], a1[32];
#pragma unroll
    for (int c = 0; c < 32; ++c) { a0[c] = bs[c]; a1[c] = bs[c]; }
    const int r0 = 2 * t, r1 = 2 * t + 1;
#pragma unroll
    for (int k = 0; k < 32; ++k) {
        const float x0 = xs[r0 * 33 + k];
        const float x1 = xs[r1 * 33 + k];
        const float4* wr = (const float4*)&Ws[k * 36];
#pragma unroll
        for (int q = 0; q < 8; ++q) {
            const float4 w = wr[q];
            a0[4 * q + 0] = fmaf(x0, w.x, a0[4 * q + 0]);
            a0[4 * q + 1] = fmaf(x0, w.y, a0[4 * q + 1]);
            a0[4 * q + 2] = fmaf(x0, w.z, a0[4 * q + 2]);
            a0[4 * q + 3] = fmaf(x0, w.w, a0[4 * q + 3]);
            a1[4 * q + 0] = fmaf(x1, w.x, a1[4 * q + 0]);
            a1[4 * q + 1] = fmaf(x1, w.y, a1[4 * q + 1]);
            a1[4 * q + 2] = fmaf(x1, w.z, a1[4 * q + 2]);
            a1[4 * q + 3] = fmaf(x1, w.w, a1[4 * q + 3]);
        }
    }
    __syncthreads();

    unsigned* os = (unsigned*)xs;
#pragma unroll
    for (int p = 0; p < 16; ++p) {
        __half2 h0 = __floats2half2_rn(a0[2 * p], a0[2 * p + 1]);
        __half2 h1 = __floats2half2_rn(a1[2 * p], a1[2 * p + 1]);
        os[r0 * 17 + p] = *(unsigned*)&h0;
        os[r1 * 17 + p] = *(unsigned*)&h1;
    }
    __syncthreads();
    unsigned* H2 = (unsigned*)H;
    const long long obase = (long long)blockIdx.x * (LIN_RPB * 16);
#pragma unroll 4
    for (int i = 0; i < (LIN_RPB * 16) / LIN_T; ++i) {
        const long long o = obase + i * LIN_T + t;
        const int flat = i * LIN_T + t;
        if (o < (long long)NNODES * 16)
            H2[o] = os[(flat >> 4) * 17 + (flat & 15)];
    }
}

// ---------------- fused aggregation (+ReLU) (+next linear, wave-local epilogue) ----------------
// 16 lanes per dst row, half2 per lane, unroll 8. Only block barrier is at kernel START
// (after W staging). Epilogue stages x into the wave's private LDS strip; same-wave DS
// ordering + wave_barrier (compiler fence) make it visible without __syncthreads.
// MODE 0: epilogue = relu + linear(W,b) -> Hout fp16.  MODE 1: epilogue = relu -> out f32.
template <int MODE>
__global__ void agg_fused3(const int* __restrict__ qrowptr, const int* __restrict__ srcSorted,
                           const __half* __restrict__ Hin, const float* __restrict__ W,
                           const float* __restrict__ b, __half* __restrict__ Hout,
                           float* __restrict__ out) {
    __shared__ float xs[16 * 33];   // wave w owns rows 4w..4w+3
    __shared__ float Ws[32 * 36];
    __shared__ float bs[32];
    const int tid = threadIdx.x;
    const int r = tid >> 4;         // row-in-block = 16-lane group id
    const int j = tid & 15;

    if (MODE == 0) {
        for (int i = tid; i < 1024; i += 256) {
            const int c = i >> 5, k = i & 31;
            Ws[k * 36 + c] = W[i];
        }
        if (tid < 32) bs[tid] = b[tid];
        __syncthreads();  // cheap: all threads just started
    }

    const int d = blockIdx.x * 16 + r;
    const unsigned int* __restrict__ H2 = (const unsigned int*)Hin;

    int e = qrowptr[d * NB];
    const int eEnd = qrowptr[d * NB + NB];
    float2 acc = __half22float2(((const __half2*)Hin)[d * 16 + j]);  // self-loop
    for (; e + 7 < eEnd; e += 8) {
        int s[8];
#pragma unroll
        for (int k = 0; k < 8; ++k) s[k] = srcSorted[e + k];
        unsigned int v[8];
#pragma unroll
        for (int k = 0; k < 8; ++k) v[k] = H2[s[k] * 16 + j];
#pragma unroll
        for (int k = 0; k < 8; ++k) {
            const float2 f = __half22float2(*(const __half2*)&v[k]);
            acc.x += f.x;
            acc.y += f.y;
        }
    }
    for (; e < eEnd; ++e) {
        const unsigned int v = H2[srcSorted[e] * 16 + j];
        const float2 f = __half22float2(*(const __half2*)&v);
        acc.x += f.x;
        acc.y += f.y;
    }

    if (MODE == 1) {
        acc.x = fmaxf(acc.x, 0.0f);
        acc.y = fmaxf(acc.y, 0.0f);
        ((float2*)out)[d * 16 + j] = acc;
        return;
    }

    // wave-local x staging (no block barrier; no straggler coupling across waves)
    xs[r * 33 + 2 * j] = fmaxf(acc.x, 0.0f);
    xs[r * 33 + 2 * j + 1] = fmaxf(acc.y, 0.0f);
    __builtin_amdgcn_wave_barrier();  // compiler fence; DS ops are in-order per wave

    float n0 = bs[2 * j], n1 = bs[2 * j + 1];
#pragma unroll
    for (int k = 0; k < 32; ++k) {
        const float x = xs[r * 33 + k];          // broadcast within 16-lane group
        n0 = fmaf(x, Ws[k * 36 + 2 * j], n0);
        n1 = fmaf(x, Ws[k * 36 + 2 * j + 1], n1);
    }
    __half2 h = __floats2half2_rn(n0, n1);
    ((unsigned*)Hout)[d * 16 + j] = *(unsigned*)&h;
}

// ---------------- launch ----------------

extern "C" void kernel_launch(void* const* d_in, const int* in_sizes, int n_in,
                              void* d_out, int out_size, void* d_ws, size_t ws_size,
                              hipStream_t stream) {
    const float* row_embed = (const float*)d_in[0];
    const float* col_embed = (const float*)d_in[1];
    const float* W0 = (const float*)d_in[2];
    const float* b0 = (const float*)d_in[3];
    const float* W1 = (const float*)d_in[4];
    const float* b1 = (const float*)d_in[5];
    const float* W2 = (const float*)d_in[6];
    const float* b2 = (const float*)d_in[7];
    const int* ei = (const int*)d_in[8];
    const int* src = ei;
    const int* dst = ei + NEDGE;
    float* out = (float*)d_out;

    // workspace carve-up (~65 MB); qrowptr ALIASES counts+bases (dead after scatter3)
    __half* H0 = (__half*)d_ws;                                       // 9.6 MB
    __half* H1 = H0 + (size_t)NNODES * D;                             // 9.6 MB
    unsigned int* binned = (unsigned int*)(H1 + (size_t)NNODES * D);  // 20 MB
    int* srcSorted = (int*)(binned + NEDGE);                          // 20 MB
    int* counts = srcSorted + NEDGE;                                  // 2.4 MB
    int* bases = counts + NCOUNTS;                                    // 2.4 MB
    int* partials = bases + NCOUNTS;                                  // 586
    int* binPtr = partials + NSCAN;                                   // NBINS+1
    int* qrowptr = counts;  // NBINS*1024+1 ints, aliases counts+bases

    const int agg_grid = NNODES / 16;  // 9375

    // CSR build — atomic-free counting sort (rebuilt every call; stateless)
    count_kernel<<<NBLK, SCT, 0, stream>>>(dst, counts);
    scanA<<<NSCAN, 256, 0, stream>>>(counts, partials);
    scanB<<<1, 256, 0, stream>>>(partials);
    scanC<<<NSCAN, 256, 0, stream>>>(counts, partials, bases, binPtr);
    scatter3<<<NBLK, SCT, 0, stream>>>(src, dst, bases, binned);
    fine_sort8<<<NBINS, 1024, 0, stream>>>(binPtr, binned, qrowptr, srcSorted);

    // layer chain: linear0, then fused agg(+linear) kernels
    linear_rows<0><<<LIN_GRID, LIN_T, 0, stream>>>(row_embed, col_embed, W0, b0, H0);
    agg_fused3<0><<<agg_grid, 256, 0, stream>>>(qrowptr, srcSorted, H0, W1, b1, H1, nullptr);
    agg_fused3<0><<<agg_grid, 256, 0, stream>>>(qrowptr, srcSorted, H1, W2, b2, H0, nullptr);
    agg_fused3<1><<<agg_grid, 256, 0, stream>>>(qrowptr, srcSorted, H0, nullptr, nullptr, nullptr, out);

    (void)in_sizes; (void)n_in; (void)out_size; (void)ws_size;
}